// Round 11
// baseline (65341.589 us; speedup 1.0000x reference)
//
#include <hip/hip_runtime.h>

#define T_STEPS 512
#define BATCH   64
#define HID     512

typedef __attribute__((ext_vector_type(8))) short short8;
typedef __attribute__((ext_vector_type(4))) float f32x4;

__device__ __forceinline__ unsigned short f2bf(float f){
  unsigned u = __float_as_uint(f);
  u += 0x7FFF + ((u >> 16) & 1);           // RNE
  return (unsigned short)(u >> 16);
}
__device__ __forceinline__ float bf2f(unsigned short s){
  return __uint_as_float(((unsigned)s) << 16);
}
__device__ __forceinline__ f32x4 mfma16(short8 a, short8 b, f32x4 c){
  return __builtin_amdgcn_mfma_f32_16x16x32_bf16(a, b, c, 0, 0, 0);
}
__device__ __forceinline__ float sigf(float x){
  return 1.0f / (1.0f + exp2f(-1.44269504f * x));
}
__device__ __forceinline__ float tanh_(float x){
  float e = exp2f(2.88539008f * x);
  return 1.0f - 2.0f / (1.0f + e);
}

// Constant-rate (100 MHz) global timer — immune to SCLK throttling.
__device__ __forceinline__ unsigned long long rtime(){
  unsigned long long t;
  asm volatile("s_memrealtime %0\n\ts_waitcnt lgkmcnt(0)" : "=s"(t));
  return t;
}

// ---- hot all-wave spin (R8, unchanged) ----
__device__ __forceinline__ void spinL0(int* flags0, int target){
  int lane = threadIdx.x & 63;
  int* p = &flags0[(lane & 31)*32];
  float a0 = 1.0f;
  int guard = 0;
  for (;;){
    int v = __hip_atomic_load(p, __ATOMIC_RELAXED, __HIP_MEMORY_SCOPE_AGENT);
    if (__ballot(v >= target) == ~0ull) break;
    #pragma unroll
    for (int i = 0; i < 8; ++i) a0 = __builtin_fmaf(a0, 1.000001f, 0.000001f);
    if (++guard > (1 << 18)) break;      // anti-hang safety
  }
  asm volatile("" :: "v"(a0));           // keep filler alive (no DCE)
  asm volatile("" ::: "memory");
  __builtin_amdgcn_fence(__ATOMIC_ACQUIRE, "workgroup");  // compiler ordering
}

__device__ __forceinline__ void spinL1(int* flags0, int* flags1, int t){
  int lane = threadIdx.x & 63;
  int* p   = (lane < 32) ? &flags0[lane*32] : &flags1[(lane-32)*32];
  int tgt  = (lane < 32) ? t + 1 : t;
  float a0 = 1.0f;
  int guard = 0;
  for (;;){
    int v = __hip_atomic_load(p, __ATOMIC_RELAXED, __HIP_MEMORY_SCOPE_AGENT);
    if (__ballot(v >= tgt) == ~0ull) break;
    #pragma unroll
    for (int i = 0; i < 8; ++i) a0 = __builtin_fmaf(a0, 1.000001f, 0.000001f);
    if (++guard > (1 << 18)) break;
  }
  asm volatile("" :: "v"(a0));
  asm volatile("" ::: "memory");
  __builtin_amdgcn_fence(__ATOMIC_ACQUIRE, "workgroup");
}

// Call AFTER __syncthreads() (which drains all waves' sc1 stores): publish step.
__device__ __forceinline__ void signalSlot(int* slot, int val){
  __builtin_amdgcn_fence(__ATOMIC_RELEASE, "workgroup");  // compiler ordering
  asm volatile("" ::: "memory");
  __hip_atomic_store(slot, val, __ATOMIC_RELAXED, __HIP_MEMORY_SCOPE_AGENT);
}

// Weight fragments: layout [tau][16 rows][K] bf16, K-contiguous.
template<int NKB>
__device__ __forceinline__ void loadB(const unsigned short* __restrict__ Wg, int K, int kstart,
                                      int l15, int l4, short8 B[4][NKB]){
  #pragma unroll
  for (int tt = 0; tt < 4; ++tt)
    #pragma unroll
    for (int kb = 0; kb < NKB; ++kb)
      B[tt][kb] = *(const short8*)(Wg + (long)(tt*16 + l15)*K + kstart + kb*32 + l4*8);
}

// acc[m][tau] += W[tau] * A[m]^T  (swapped operands: D col=batch, row=gate)
template<int NKB>
__device__ __forceinline__ void gemmA(const unsigned short* __restrict__ Ab, long rs,
                                      int l15, int l4, const short8 B[4][NKB], f32x4 acc[4][4]){
  #pragma unroll
  for (int kb = 0; kb < NKB; ++kb){
    short8 a[4];
    #pragma unroll
    for (int m = 0; m < 4; ++m)
      a[m] = *(const short8*)(Ab + (long)(m*16 + l15)*rs + kb*32 + l4*8);
    #pragma unroll
    for (int m = 0; m < 4; ++m)
      #pragma unroll
      for (int tt = 0; tt < 4; ++tt)
        acc[m][tt] = mfma16(B[tt][kb], a[m], acc[m][tt]);
  }
}

// All-to-all K-partial reduce through LDS. Wave w finalizes batch-tile m==w.
__device__ __forceinline__ void reduceWrite(float* red, int w, int l15, int l4, f32x4 acc[4][4]){
  #pragma unroll
  for (int m = 0; m < 4; ++m){
    if (m == w) continue;
    int mi = (m > w) ? m - 1 : m;
    #pragma unroll
    for (int tt = 0; tt < 4; ++tt){
      float* p = red + (w*12 + mi*4 + tt)*320 + l15*20 + l4*4;
      *(f32x4*)p = acc[m][tt];
    }
  }
}
__device__ __forceinline__ void reduceRead(const float* red, int w, int l15, int l4,
                                           f32x4 gf[4], f32x4 acc[4][4]){
  #pragma unroll
  for (int tt = 0; tt < 4; ++tt) gf[tt] = acc[w][tt];
  #pragma unroll
  for (int v = 0; v < 4; ++v){
    if (v == w) continue;
    int mi = (w > v) ? w - 1 : w;
    #pragma unroll
    for (int tt = 0; tt < 4; ++tt){
      const float* p = red + (v*12 + mi*4 + tt)*320 + l15*20 + l4*4;
      gf[tt] += *(const f32x4*)p;
    }
  }
}

// Gate math + packed 8B agent-coherent h store.
__device__ __forceinline__ void gatesStore(f32x4 gf[4], f32x4& cst,
                                           unsigned short* __restrict__ hdst){
  f32x4 hh;
  #pragma unroll
  for (int r = 0; r < 4; ++r){
    float iv = sigf(gf[0][r]), fv = sigf(gf[1][r]);
    float gv = tanh_(gf[2][r]), ov = sigf(gf[3][r]);
    float cv = fv * cst[r] + iv * gv;
    cst[r] = cv;
    hh[r] = ov * tanh_(cv);
  }
  unsigned long long pk = (unsigned long long)f2bf(hh[0])
    | ((unsigned long long)f2bf(hh[1]) << 16)
    | ((unsigned long long)f2bf(hh[2]) << 32)
    | ((unsigned long long)f2bf(hh[3]) << 48);
  __hip_atomic_store((unsigned long long*)hdst, pk, __ATOMIC_RELAXED, __HIP_MEMORY_SCOPE_AGENT);
}

// ---------------- layer 0 recurrent (R8 + phase instrumentation) ----------------
template<int NXB, int NHB>
__device__ void l0_loop(int g, int w, int lane,
                        const unsigned short* __restrict__ Wg,
                        const float* __restrict__ bias0,
                        const unsigned short* __restrict__ xb,
                        unsigned short* __restrict__ h0seq,
                        int* flags0, float* red, int hk0,
                        unsigned long long* probe){
  int l15 = lane & 15, l4 = lane >> 4;
  short8 Bx[4][(NXB > 0) ? NXB : 1];
  if constexpr (NXB > 0) loadB<NXB>(Wg, 576, 0, l15, l4, Bx);
  short8 Bh[4][NHB];
  loadB<NHB>(Wg, 576, 64 + hk0, l15, l4, Bh);
  f32x4 bsv[4];
  #pragma unroll
  for (int tt = 0; tt < 4; ++tt) bsv[tt] = *(const f32x4*)&bias0[(g*4 + tt)*16 + l4*4];
  f32x4 cst = {0.f, 0.f, 0.f, 0.f};
  int b = w*16 + l15, colb = g*16 + l4*4;

  const bool prb = (g == 0) && (w == 0);
  unsigned long long accA = 0, accT = 0;

  for (int t = 0; t < T_STEPS; ++t){
    unsigned long long r0 = prb ? rtime() : 0;
    f32x4 acc[4][4];
    #pragma unroll
    for (int m = 0; m < 4; ++m)
      #pragma unroll
      for (int tt = 0; tt < 4; ++tt) acc[m][tt] = (f32x4){0.f,0.f,0.f,0.f};
    // x-contribution is independent of h[t-1]: compute before the wait
    if constexpr (NXB > 0)
      gemmA<NXB>(xb + (long)t*64, (long)T_STEPS*64, l15, l4, Bx, acc);
    if (t){
      unsigned long long s0 = prb ? rtime() : 0;
      spinL0(flags0, t);                  // hot spin, all waves
      if (prb) accA += rtime() - s0;
      gemmA<NHB>(h0seq + (long)(t-1)*BATCH*HID + hk0, HID, l15, l4, Bh, acc);
    }
    reduceWrite(red, w, l15, l4, acc);
    __syncthreads();
    f32x4 gf[4];
    reduceRead(red, w, l15, l4, gf, acc);
    #pragma unroll
    for (int tt = 0; tt < 4; ++tt) gf[tt] += bsv[tt];
    gatesStore(gf, cst, h0seq + (long)t*BATCH*HID + (long)b*HID + colb);
    __syncthreads();                      // drains all waves' sc1 stores; guards red reuse
    if (threadIdx.x == 0) signalSlot(&flags0[g*32], t + 1);
    if (prb) accT += rtime() - r0;
  }
  if (prb && lane == 0){
    __hip_atomic_store(&probe[0], accA, __ATOMIC_RELAXED, __HIP_MEMORY_SCOPE_AGENT);
    __hip_atomic_store(&probe[1], accT, __ATOMIC_RELAXED, __HIP_MEMORY_SCOPE_AGENT);
  }
}

// ---------------- layer 1: fused W_ih1@h0[t] + W_hh1@h1[t-1] (K=1024) ----------------
__device__ void l1_loop(int g, int w, int lane,
                        const unsigned short* __restrict__ Wg,
                        const float* __restrict__ bias1,
                        const unsigned short* __restrict__ h0seq,
                        unsigned short* __restrict__ h1seq,
                        int* flags0, int* flags1, float* red){
  int l15 = lane & 15, l4 = lane >> 4;
  short8 Bh[4][8];
  loadB<8>(Wg, 1024, w*256, l15, l4, Bh);
  f32x4 bsv[4];
  #pragma unroll
  for (int tt = 0; tt < 4; ++tt) bsv[tt] = *(const f32x4*)&bias1[(g*4 + tt)*16 + l4*4];
  f32x4 cst = {0.f, 0.f, 0.f, 0.f};
  int b = w*16 + l15, colb = g*16 + l4*4;

  for (int t = 0; t < T_STEPS; ++t){
    spinL1(flags0, flags1, t);            // hot spin, all waves
    f32x4 acc[4][4];
    #pragma unroll
    for (int m = 0; m < 4; ++m)
      #pragma unroll
      for (int tt = 0; tt < 4; ++tt) acc[m][tt] = (f32x4){0.f,0.f,0.f,0.f};
    if (w < 2)
      gemmA<8>(h0seq + (long)t*BATCH*HID + w*256, HID, l15, l4, Bh, acc);
    else if (t)
      gemmA<8>(h1seq + (long)(t-1)*BATCH*HID + (w-2)*256, HID, l15, l4, Bh, acc);
    reduceWrite(red, w, l15, l4, acc);
    __syncthreads();
    f32x4 gf[4];
    reduceRead(red, w, l15, l4, gf, acc);
    #pragma unroll
    for (int tt = 0; tt < 4; ++tt) gf[tt] += bsv[tt];
    gatesStore(gf, cst, h1seq + (long)t*BATCH*HID + (long)b*HID + colb);
    __syncthreads();
    if (threadIdx.x == 0) signalSlot(&flags1[g*32], t + 1);
  }
}

// ---------------- persistent kernel ----------------
extern "C" __global__ void __launch_bounds__(256, 1)
lstm_persist(const unsigned short* __restrict__ Wpk0,
             const unsigned short* __restrict__ Wpk1,
             const float* __restrict__ bias0, const float* __restrict__ bias1,
             const unsigned short* __restrict__ xb,
             unsigned short* __restrict__ h0seq, unsigned short* __restrict__ h1seq,
             int* flags0, int* flags1, unsigned long long* probe){
  __shared__ float red[15360];   // 60 KB reduce buffer
  int wg = blockIdx.x;
  int role = wg >> 5;
  int g = wg & 31;
  int w = threadIdx.x >> 6;
  int lane = threadIdx.x & 63;

  if (role == 0){
    const unsigned short* Wg = Wpk0 + (long)g*4*16*576;
    switch (w){
      case 0:  l0_loop<2,3>(g, 0, lane, Wg, bias0, xb, h0seq, flags0, red, 0,   probe); break;
      case 1:  l0_loop<0,5>(g, 1, lane, Wg, bias0, xb, h0seq, flags0, red, 96,  probe); break;
      case 2:  l0_loop<0,4>(g, 2, lane, Wg, bias0, xb, h0seq, flags0, red, 256, probe); break;
      default: l0_loop<0,4>(g, 3, lane, Wg, bias0, xb, h0seq, flags0, red, 384, probe); break;
    }
  } else {
    const unsigned short* Wg = Wpk1 + (long)g*4*16*1024;
    l1_loop(g, w, lane, Wg, bias1, h0seq, h1seq, flags0, flags1, red);
  }
}

// ---------------- echo: encode probe values into rocprof-visible channels ----
// dur_us  = 60000 + accA/100   (total L0-WG0 spin-wait, us)
// WRITE_SIZE ~= (accT-accA)/256 KB  (total L0-WG0 work time, via agent stores)
extern "C" __global__ void echo_kernel(const unsigned long long* __restrict__ probe,
                                       unsigned int* __restrict__ wreg){
  __shared__ unsigned long long sA, sW;
  if (threadIdx.x == 0){
    unsigned long long A = probe[0];
    unsigned long long T = probe[1];
    if (A > 3000000ull) A = 3000000ull;            // cap: +30ms sentinel
    unsigned long long W = (T > A) ? (T - A) : 0;
    if (W > 3000000ull) W = 3000000ull;
    sA = A; sW = W;
  }
  __syncthreads();
  unsigned long long A = sA, W = sW;
  // WRITE channel: W/16 distinct 64B lines, agent write-through stores
  unsigned long long lines = W >> 4;
  for (unsigned long long i = threadIdx.x; i < lines; i += blockDim.x)
    __hip_atomic_store(&wreg[i*16], (unsigned)i, __ATOMIC_RELAXED, __HIP_MEMORY_SCOPE_AGENT);
  // dur channel: busy-wait on the constant-rate timer
  unsigned long long target = 6000000ull + A;      // 60ms + A ticks
  unsigned long long t0 = rtime();
  while (rtime() - t0 < target) {}
}

// ---------------- prep: repack weights, convert x, zero flags ----------------
extern "C" __global__ void prep_kernel(const float* __restrict__ x,
    const float* __restrict__ Wih0, const float* __restrict__ Whh0,
    const float* __restrict__ bih0, const float* __restrict__ bhh0,
    const float* __restrict__ Wih1, const float* __restrict__ Whh1,
    const float* __restrict__ bih1, const float* __restrict__ bhh1,
    unsigned short* __restrict__ Wpk0, unsigned short* __restrict__ Wpk1,
    float* __restrict__ bias0, float* __restrict__ bias1,
    unsigned short* __restrict__ xb, int* __restrict__ syncm){
  long gid = (long)blockIdx.x * blockDim.x + threadIdx.x;
  long gs  = (long)gridDim.x * blockDim.x;
  const long NW0 = 32L*4*16*576;
  const long NW1 = 32L*4*16*1024;
  const long NX  = 64L*512*64;

  for (long i = gid; i < NW0; i += gs){
    int k = (int)(i % 576);
    long q = i / 576;
    int r  = (int)(q & 15);
    long q2 = q >> 4;
    int tt = (int)(q2 & 3);
    int g  = (int)(q2 >> 2);
    int row = tt*512 + g*16 + r;
    float v = (k < 64) ? Wih0[(long)row*64 + k] : Whh0[(long)row*512 + (k - 64)];
    Wpk0[i] = f2bf(v);
  }
  for (long i = gid; i < NW1; i += gs){
    int k = (int)(i & 1023);
    long q = i >> 10;
    int r  = (int)(q & 15);
    long q2 = q >> 4;
    int tt = (int)(q2 & 3);
    int g  = (int)(q2 >> 2);
    int row = tt*512 + g*16 + r;
    float v = (k < 512) ? Wih1[(long)row*512 + k] : Whh1[(long)row*512 + (k - 512)];
    Wpk1[i] = f2bf(v);
  }
  for (long i = gid; i < 2048; i += gs){
    int r = (int)(i & 15);
    int tt = (int)((i >> 4) & 3);
    int g  = (int)(i >> 6);
    int row = tt*512 + g*16 + r;
    bias0[i] = bih0[row] + bhh0[row];
    bias1[i] = bih1[row] + bhh1[row];
  }
  for (long i = gid; i < NX; i += gs) xb[i] = f2bf(x[i]);
  for (long i = gid; i < 2048; i += gs) syncm[i] = 0;   // flags0[1024] + flags1[1024]
}

// ---------------- head: out[b,t] = h1[t,b,:] . wfc + bfc ----------------
extern "C" __global__ void head_kernel(const unsigned short* __restrict__ h1seq,
    const float* __restrict__ wfc, const float* __restrict__ bfc,
    float* __restrict__ out){
  int t = blockIdx.x;
  int tid = threadIdx.x;
  int b = tid >> 2, q = tid & 3;
  const unsigned short* hp = h1seq + ((long)t*BATCH + b)*HID + q*128;
  const float* wp = wfc + q*128;
  float s = 0.f;
  #pragma unroll
  for (int i = 0; i < 16; ++i){
    short8 v = *(const short8*)(hp + i*8);
    #pragma unroll
    for (int e = 0; e < 8; ++e)
      s += bf2f((unsigned short)v[e]) * wp[i*8 + e];
  }
  s += __shfl_xor(s, 1, 64);
  s += __shfl_xor(s, 2, 64);
  if (q == 0) out[(long)b*T_STEPS + t] = s + bfc[0];
}

extern "C" void kernel_launch(void* const* d_in, const int* in_sizes, int n_in,
                              void* d_out, int out_size, void* d_ws, size_t ws_size,
                              hipStream_t stream){
  const float* x    = (const float*)d_in[0];
  const float* Wih0 = (const float*)d_in[1];
  const float* Whh0 = (const float*)d_in[2];
  const float* bih0 = (const float*)d_in[3];
  const float* bhh0 = (const float*)d_in[4];
  const float* Wih1 = (const float*)d_in[5];
  const float* Whh1 = (const float*)d_in[6];
  const float* bih1 = (const float*)d_in[7];
  const float* bhh1 = (const float*)d_in[8];
  const float* wfc  = (const float*)d_in[9];
  const float* bfc  = (const float*)d_in[10];
  float* out = (float*)d_out;

  char* p = (char*)d_ws;
  auto carve = [&](size_t bytes) -> void* {
    void* r = (void*)p;
    p += (bytes + 255) & ~(size_t)255;
    return r;
  };
  unsigned short* Wpk0  = (unsigned short*)carve(32L*4*16*576*2);
  unsigned short* Wpk1  = (unsigned short*)carve(32L*4*16*1024*2);
  float* bias0 = (float*)carve(2048*4);
  float* bias1 = (float*)carve(2048*4);
  unsigned short* xb    = (unsigned short*)carve(64L*512*64*2);
  unsigned short* h0seq = (unsigned short*)carve(512L*64*512*2);
  unsigned short* h1seq = (unsigned short*)carve(512L*64*512*2);
  int* syncm   = (int*)carve(8192);
  int* flags0 = syncm;           // 32 slots x 32-int stride (128B lines)
  int* flags1 = syncm + 1024;
  unsigned long long* probe = (unsigned long long*)carve(256);
  unsigned int* wreg = (unsigned int*)carve(16L*1024*1024);

  hipLaunchKernelGGL(prep_kernel, dim3(1024), dim3(256), 0, stream,
                     x, Wih0, Whh0, bih0, bhh0, Wih1, Whh1, bih1, bhh1,
                     Wpk0, Wpk1, bias0, bias1, xb, syncm);
  hipLaunchKernelGGL(lstm_persist, dim3(64), dim3(256), 0, stream,
                     Wpk0, Wpk1, bias0, bias1, xb, h0seq, h1seq, flags0, flags1, probe);
  hipLaunchKernelGGL(echo_kernel, dim3(1), dim3(256), 0, stream, probe, wreg);
  hipLaunchKernelGGL(head_kernel, dim3(512), dim3(256), 0, stream,
                     h1seq, wfc, bfc, out);
}

// Round 12
// 5907.700 us; speedup vs baseline: 11.0604x; 11.0604x over previous
//
#include <hip/hip_runtime.h>

#define T_STEPS 512
#define BATCH   64
#define HID     512

typedef __attribute__((ext_vector_type(8))) short short8;
typedef __attribute__((ext_vector_type(4))) float f32x4;

__device__ __forceinline__ unsigned short f2bf(float f){
  unsigned u = __float_as_uint(f);
  u += 0x7FFF + ((u >> 16) & 1);           // RNE
  return (unsigned short)(u >> 16);
}
__device__ __forceinline__ float bf2f(unsigned short s){
  return __uint_as_float(((unsigned)s) << 16);
}
__device__ __forceinline__ f32x4 mfma16(short8 a, short8 b, f32x4 c){
  return __builtin_amdgcn_mfma_f32_16x16x32_bf16(a, b, c, 0, 0, 0);
}
__device__ __forceinline__ float sigf(float x){
  return 1.0f / (1.0f + exp2f(-1.44269504f * x));
}
__device__ __forceinline__ float tanh_(float x){
  float e = exp2f(2.88539008f * x);
  return 1.0f - 2.0f / (1.0f + e);
}

__device__ __forceinline__ int aload(const int* p){
  return __hip_atomic_load(p, __ATOMIC_RELAXED, __HIP_MEMORY_SCOPE_AGENT);
}

// Monotonic-flag spin with per-lane caching: lanes whose cached value already
// meets the target issue NO loads (flags only grow). Ballot over cached state.
__device__ __forceinline__ void spinF(int* flags, int target, int& lastv){
  int lane = threadIdx.x & 63;
  int* p = &flags[(lane & 31)*32];
  int guard = 0;
  while (__ballot(lastv >= target) != ~0ull){
    if (lastv < target)
      lastv = aload(p);
    if (++guard > (1 << 18)) break;      // anti-hang safety
  }
  asm volatile("" ::: "memory");
  __builtin_amdgcn_fence(__ATOMIC_ACQUIRE, "workgroup");  // compiler ordering
}

// Call AFTER __syncthreads() (which drains all waves' sc1 stores): publish step.
__device__ __forceinline__ void signalSlot(int* slot, int val){
  __builtin_amdgcn_fence(__ATOMIC_RELEASE, "workgroup");  // compiler ordering
  asm volatile("" ::: "memory");
  __hip_atomic_store(slot, val, __ATOMIC_RELAXED, __HIP_MEMORY_SCOPE_AGENT);
}

// Weight fragments: layout [tau][16 rows][K] bf16, K-contiguous.
template<int NKB>
__device__ __forceinline__ void loadB(const unsigned short* __restrict__ Wg, int K, int kstart,
                                      int l15, int l4, short8 B[4][NKB]){
  #pragma unroll
  for (int tt = 0; tt < 4; ++tt)
    #pragma unroll
    for (int kb = 0; kb < NKB; ++kb)
      B[tt][kb] = *(const short8*)(Wg + (long)(tt*16 + l15)*K + kstart + kb*32 + l4*8);
}

// acc[m][tau] += W[tau] * A[m]^T  (swapped operands: D col=batch, row=gate)
template<int NKB>
__device__ __forceinline__ void gemmA(const unsigned short* __restrict__ Ab, long rs,
                                      int l15, int l4, const short8 B[4][NKB], f32x4 acc[4][4]){
  #pragma unroll
  for (int kb = 0; kb < NKB; ++kb){
    short8 a[4];
    #pragma unroll
    for (int m = 0; m < 4; ++m)
      a[m] = *(const short8*)(Ab + (long)(m*16 + l15)*rs + kb*32 + l4*8);
    #pragma unroll
    for (int m = 0; m < 4; ++m)
      #pragma unroll
      for (int tt = 0; tt < 4; ++tt)
        acc[m][tt] = mfma16(B[tt][kb], a[m], acc[m][tt]);
  }
}

// All-to-all K-partial reduce through LDS. Wave w finalizes batch-tile m==w.
__device__ __forceinline__ void reduceWrite(float* red, int w, int l15, int l4, f32x4 acc[4][4]){
  #pragma unroll
  for (int m = 0; m < 4; ++m){
    if (m == w) continue;
    int mi = (m > w) ? m - 1 : m;
    #pragma unroll
    for (int tt = 0; tt < 4; ++tt){
      float* p = red + (w*12 + mi*4 + tt)*320 + l15*20 + l4*4;
      *(f32x4*)p = acc[m][tt];
    }
  }
}
__device__ __forceinline__ void reduceRead(const float* red, int w, int l15, int l4,
                                           f32x4 gf[4], f32x4 acc[4][4]){
  #pragma unroll
  for (int tt = 0; tt < 4; ++tt) gf[tt] = acc[w][tt];
  #pragma unroll
  for (int v = 0; v < 4; ++v){
    if (v == w) continue;
    int mi = (w > v) ? w - 1 : w;
    #pragma unroll
    for (int tt = 0; tt < 4; ++tt){
      const float* p = red + (v*12 + mi*4 + tt)*320 + l15*20 + l4*4;
      gf[tt] += *(const f32x4*)p;
    }
  }
}

// Gate math + packed 8B agent-coherent h store.
__device__ __forceinline__ void gatesStore(f32x4 gf[4], f32x4& cst,
                                           unsigned short* __restrict__ hdst){
  f32x4 hh;
  #pragma unroll
  for (int r = 0; r < 4; ++r){
    float iv = sigf(gf[0][r]), fv = sigf(gf[1][r]);
    float gv = tanh_(gf[2][r]), ov = sigf(gf[3][r]);
    float cv = fv * cst[r] + iv * gv;
    cst[r] = cv;
    hh[r] = ov * tanh_(cv);
  }
  unsigned long long pk = (unsigned long long)f2bf(hh[0])
    | ((unsigned long long)f2bf(hh[1]) << 16)
    | ((unsigned long long)f2bf(hh[2]) << 32)
    | ((unsigned long long)f2bf(hh[3]) << 48);
  __hip_atomic_store((unsigned long long*)hdst, pk, __ATOMIC_RELAXED, __HIP_MEMORY_SCOPE_AGENT);
}

// ---------------- layer 0 recurrent ----------------
template<int NXB, int NHB>
__device__ void l0_loop(int g, int w, int lane,
                        const unsigned short* __restrict__ Wg,
                        const float* __restrict__ bias0,
                        const unsigned short* __restrict__ xb,
                        unsigned short* __restrict__ h0seq,
                        int* flags0, float* red, int hk0){
  int l15 = lane & 15, l4 = lane >> 4;
  short8 Bx[4][(NXB > 0) ? NXB : 1];
  if constexpr (NXB > 0) loadB<NXB>(Wg, 576, 0, l15, l4, Bx);
  short8 Bh[4][NHB];
  loadB<NHB>(Wg, 576, 64 + hk0, l15, l4, Bh);
  f32x4 bsv[4];
  #pragma unroll
  for (int tt = 0; tt < 4; ++tt) bsv[tt] = *(const f32x4*)&bias0[(g*4 + tt)*16 + l4*4];
  f32x4 cst = {0.f, 0.f, 0.f, 0.f};
  int b = w*16 + l15, colb = g*16 + l4*4;
  int lastv = 0;

  for (int t = 0; t < T_STEPS; ++t){
    f32x4 acc[4][4];
    #pragma unroll
    for (int m = 0; m < 4; ++m)
      #pragma unroll
      for (int tt = 0; tt < 4; ++tt) acc[m][tt] = (f32x4){0.f,0.f,0.f,0.f};
    // x-contribution is independent of h[t-1]: compute before the wait
    if constexpr (NXB > 0)
      gemmA<NXB>(xb + (long)t*64, (long)T_STEPS*64, l15, l4, Bx, acc);
    if (t){
      spinF(flags0, t, lastv);            // detect hidden behind x-gemm where present
      gemmA<NHB>(h0seq + (long)(t-1)*BATCH*HID + hk0, HID, l15, l4, Bh, acc);
    }
    reduceWrite(red, w, l15, l4, acc);
    __syncthreads();
    f32x4 gf[4];
    reduceRead(red, w, l15, l4, gf, acc);
    #pragma unroll
    for (int tt = 0; tt < 4; ++tt) gf[tt] += bsv[tt];
    gatesStore(gf, cst, h0seq + (long)t*BATCH*HID + (long)b*HID + colb);
    __syncthreads();                      // drains all waves' sc1 stores; guards red reuse
    if (threadIdx.x == 0) signalSlot(&flags0[g*32], t + 1);
  }
}

// ------- layer 1: K=128/wave split of BOTH W_ih1 (pre-spin) and W_hh1 (critical) -------
__device__ void l1_loop(int g, int w, int lane,
                        const unsigned short* __restrict__ Wg,
                        const float* __restrict__ bias1,
                        const unsigned short* __restrict__ h0seq,
                        unsigned short* __restrict__ h1seq,
                        int* flags0, int* flags1, float* red){
  int l15 = lane & 15, l4 = lane >> 4;
  short8 Bh0[4][4], Bh1[4][4];
  loadB<4>(Wg, 1024, w*128,       l15, l4, Bh0);   // W_ih1 K-slice
  loadB<4>(Wg, 1024, 512 + w*128, l15, l4, Bh1);   // W_hh1 K-slice
  f32x4 bsv[4];
  #pragma unroll
  for (int tt = 0; tt < 4; ++tt) bsv[tt] = *(const f32x4*)&bias1[(g*4 + tt)*16 + l4*4];
  f32x4 cst = {0.f, 0.f, 0.f, 0.f};
  int b = w*16 + l15, colb = g*16 + l4*4;
  int lastv0 = 0, lastv1 = 0;
  int* p1 = &flags1[(lane & 31)*32];

  for (int t = 0; t < T_STEPS; ++t){
    // Prefetch one flags1 observation: load issues now, is consumed after the
    // h0-gemm -> detect latency overlaps independent work.
    int v1pre = (t && lastv1 < t) ? aload(p1) : lastv1;
    f32x4 acc[4][4];
    #pragma unroll
    for (int m = 0; m < 4; ++m)
      #pragma unroll
      for (int tt = 0; tt < 4; ++tt) acc[m][tt] = (f32x4){0.f,0.f,0.f,0.f};
    spinF(flags0, t + 1, lastv0);         // L0 runs ahead -> cached, usually 0 loads
    gemmA<4>(h0seq + (long)t*BATCH*HID + w*128, HID, l15, l4, Bh0, acc);
    if (t){
      lastv1 = (v1pre > lastv1) ? v1pre : lastv1;
      spinF(flags1, t, lastv1);           // only K=128 h1-gemm sits behind this
      gemmA<4>(h1seq + (long)(t-1)*BATCH*HID + w*128, HID, l15, l4, Bh1, acc);
    }
    reduceWrite(red, w, l15, l4, acc);
    __syncthreads();
    f32x4 gf[4];
    reduceRead(red, w, l15, l4, gf, acc);
    #pragma unroll
    for (int tt = 0; tt < 4; ++tt) gf[tt] += bsv[tt];
    gatesStore(gf, cst, h1seq + (long)t*BATCH*HID + (long)b*HID + colb);
    __syncthreads();
    if (threadIdx.x == 0) signalSlot(&flags1[g*32], t + 1);
  }
}

// ---------------- persistent kernel ----------------
extern "C" __global__ void __launch_bounds__(256, 1)
lstm_persist(const unsigned short* __restrict__ Wpk0,
             const unsigned short* __restrict__ Wpk1,
             const float* __restrict__ bias0, const float* __restrict__ bias1,
             const unsigned short* __restrict__ xb,
             unsigned short* __restrict__ h0seq, unsigned short* __restrict__ h1seq,
             int* flags0, int* flags1){
  __shared__ float red[15360];   // 60 KB reduce buffer
  int wg = blockIdx.x;
  int role = wg >> 5;
  int g = wg & 31;
  int w = threadIdx.x >> 6;
  int lane = threadIdx.x & 63;

  if (role == 0){
    const unsigned short* Wg = Wpk0 + (long)g*4*16*576;
    switch (w){
      case 0:  l0_loop<2,3>(g, 0, lane, Wg, bias0, xb, h0seq, flags0, red, 0);   break;
      case 1:  l0_loop<0,5>(g, 1, lane, Wg, bias0, xb, h0seq, flags0, red, 96);  break;
      case 2:  l0_loop<0,4>(g, 2, lane, Wg, bias0, xb, h0seq, flags0, red, 256); break;
      default: l0_loop<0,4>(g, 3, lane, Wg, bias0, xb, h0seq, flags0, red, 384); break;
    }
  } else {
    const unsigned short* Wg = Wpk1 + (long)g*4*16*1024;
    l1_loop(g, w, lane, Wg, bias1, h0seq, h1seq, flags0, flags1, red);
  }
}

// ---------------- prep: repack weights, convert x, zero flags ----------------
extern "C" __global__ void prep_kernel(const float* __restrict__ x,
    const float* __restrict__ Wih0, const float* __restrict__ Whh0,
    const float* __restrict__ bih0, const float* __restrict__ bhh0,
    const float* __restrict__ Wih1, const float* __restrict__ Whh1,
    const float* __restrict__ bih1, const float* __restrict__ bhh1,
    unsigned short* __restrict__ Wpk0, unsigned short* __restrict__ Wpk1,
    float* __restrict__ bias0, float* __restrict__ bias1,
    unsigned short* __restrict__ xb, int* __restrict__ syncm){
  long gid = (long)blockIdx.x * blockDim.x + threadIdx.x;
  long gs  = (long)gridDim.x * blockDim.x;
  const long NW0 = 32L*4*16*576;
  const long NW1 = 32L*4*16*1024;
  const long NX  = 64L*512*64;

  for (long i = gid; i < NW0; i += gs){
    int k = (int)(i % 576);
    long q = i / 576;
    int r  = (int)(q & 15);
    long q2 = q >> 4;
    int tt = (int)(q2 & 3);
    int g  = (int)(q2 >> 2);
    int row = tt*512 + g*16 + r;
    float v = (k < 64) ? Wih0[(long)row*64 + k] : Whh0[(long)row*512 + (k - 64)];
    Wpk0[i] = f2bf(v);
  }
  for (long i = gid; i < NW1; i += gs){
    int k = (int)(i & 1023);
    long q = i >> 10;
    int r  = (int)(q & 15);
    long q2 = q >> 4;
    int tt = (int)(q2 & 3);
    int g  = (int)(q2 >> 2);
    int row = tt*512 + g*16 + r;
    float v = (k < 512) ? Wih1[(long)row*512 + k] : Whh1[(long)row*512 + (k - 512)];
    Wpk1[i] = f2bf(v);
  }
  for (long i = gid; i < 2048; i += gs){
    int r = (int)(i & 15);
    int tt = (int)((i >> 4) & 3);
    int g  = (int)(i >> 6);
    int row = tt*512 + g*16 + r;
    bias0[i] = bih0[row] + bhh0[row];
    bias1[i] = bih1[row] + bhh1[row];
  }
  for (long i = gid; i < NX; i += gs) xb[i] = f2bf(x[i]);
  for (long i = gid; i < 2048; i += gs) syncm[i] = 0;   // flags0[1024] + flags1[1024]
}

// ---------------- head: out[b,t] = h1[t,b,:] . wfc + bfc ----------------
extern "C" __global__ void head_kernel(const unsigned short* __restrict__ h1seq,
    const float* __restrict__ wfc, const float* __restrict__ bfc,
    float* __restrict__ out){
  int t = blockIdx.x;
  int tid = threadIdx.x;
  int b = tid >> 2, q = tid & 3;
  const unsigned short* hp = h1seq + ((long)t*BATCH + b)*HID + q*128;
  const float* wp = wfc + q*128;
  float s = 0.f;
  #pragma unroll
  for (int i = 0; i < 16; ++i){
    short8 v = *(const short8*)(hp + i*8);
    #pragma unroll
    for (int e = 0; e < 8; ++e)
      s += bf2f((unsigned short)v[e]) * wp[i*8 + e];
  }
  s += __shfl_xor(s, 1, 64);
  s += __shfl_xor(s, 2, 64);
  if (q == 0) out[(long)b*T_STEPS + t] = s + bfc[0];
}

extern "C" void kernel_launch(void* const* d_in, const int* in_sizes, int n_in,
                              void* d_out, int out_size, void* d_ws, size_t ws_size,
                              hipStream_t stream){
  const float* x    = (const float*)d_in[0];
  const float* Wih0 = (const float*)d_in[1];
  const float* Whh0 = (const float*)d_in[2];
  const float* bih0 = (const float*)d_in[3];
  const float* bhh0 = (const float*)d_in[4];
  const float* Wih1 = (const float*)d_in[5];
  const float* Whh1 = (const float*)d_in[6];
  const float* bih1 = (const float*)d_in[7];
  const float* bhh1 = (const float*)d_in[8];
  const float* wfc  = (const float*)d_in[9];
  const float* bfc  = (const float*)d_in[10];
  float* out = (float*)d_out;

  char* p = (char*)d_ws;
  auto carve = [&](size_t bytes) -> void* {
    void* r = (void*)p;
    p += (bytes + 255) & ~(size_t)255;
    return r;
  };
  unsigned short* Wpk0  = (unsigned short*)carve(32L*4*16*576*2);
  unsigned short* Wpk1  = (unsigned short*)carve(32L*4*16*1024*2);
  float* bias0 = (float*)carve(2048*4);
  float* bias1 = (float*)carve(2048*4);
  unsigned short* xb    = (unsigned short*)carve(64L*512*64*2);
  unsigned short* h0seq = (unsigned short*)carve(512L*64*512*2);
  unsigned short* h1seq = (unsigned short*)carve(512L*64*512*2);
  int* syncm   = (int*)carve(8192);
  int* flags0 = syncm;           // 32 slots x 32-int stride (128B lines)
  int* flags1 = syncm + 1024;

  hipLaunchKernelGGL(prep_kernel, dim3(1024), dim3(256), 0, stream,
                     x, Wih0, Whh0, bih0, bhh0, Wih1, Whh1, bih1, bhh1,
                     Wpk0, Wpk1, bias0, bias1, xb, syncm);
  hipLaunchKernelGGL(lstm_persist, dim3(64), dim3(256), 0, stream,
                     Wpk0, Wpk1, bias0, bias1, xb, h0seq, h1seq, flags0, flags1);
  hipLaunchKernelGGL(head_kernel, dim3(512), dim3(256), 0, stream,
                     h1seq, wfc, bfc, out);
}